// Round 8
// baseline (332.471 us; speedup 1.0000x reference)
//
#include <hip/hip_runtime.h>

#define S 256
#define D 256
#define DFF 1024

typedef unsigned int uint32;

// ---------------- wave helpers ----------------
__device__ __forceinline__ float wave_sum(float v) {
#pragma unroll
    for (int o = 32; o; o >>= 1) v += __shfl_xor(v, o, 64);
    return v;
}
__device__ __forceinline__ float wave_max(float v) {
#pragma unroll
    for (int o = 32; o; o >>= 1) v = fmaxf(v, __shfl_xor(v, o, 64));
    return v;
}
__device__ __forceinline__ uint32 bf16rne(float f) {
    uint32 u = __float_as_uint(f);
    return (u + 0x7fffu + ((u >> 16) & 1u)) >> 16;
}

// ---------- K0: convert+pack all weights to bf16 row-pairs ----------
// dst dword i holds rows (2p,2p+1) of col c: lo=row 2p, hi=row 2p+1.
// regions (pair-dwords): wW 65536 | nnW1 65536 | outW 65536 | ffnW1 262144 | ffnW2 262144
__global__ __launch_bounds__(256) void k_cvt(
    const float* __restrict__ wW, const float* __restrict__ nn,
    const float* __restrict__ ow, const float* __restrict__ f1w,
    const float* __restrict__ f2w, uint32* __restrict__ dst)
{
    int i = blockIdx.x * 256 + threadIdx.x;   // grid sized exactly: 2816*256 = 720896
    const float* src; int local, c;
    if (i < 65536)       { src = wW;  local = i;          c = local & 255; }
    else if (i < 131072) { src = nn;  local = i - 65536;  c = local & 255; }
    else if (i < 196608) { src = ow;  local = i - 131072; c = local & 255; }
    else if (i < 458752) { src = f1w; local = i - 196608; c = local & 1023; }
    else                 { src = f2w; local = i - 458752; c = local & 255; }
    int N = (i >= 196608 && i < 458752) ? 1024 : 256;
    float a0 = src[2 * local - c];
    float a1 = src[2 * local - c + N];
    dst[i] = (bf16rne(a1) << 16) | bf16rne(a0);
}

// ---------- K1: embedding + positional encoding (grid 512, block 256) ----------
__global__ __launch_bounds__(256) void k_embed(
    const int* __restrict__ x, const float* __restrict__ mask,
    const int* __restrict__ use_pos, const float* __restrict__ pos_enc,
    const float* __restrict__ emb_W, const float* __restrict__ emb_b,
    float* __restrict__ h)
{
    __shared__ float red[4];
    int r = blockIdx.x, d = threadIdx.x;
    int b = r >> 8, s = r & 255;
    float mv = (d <= s) ? (1.0f - mask[b * S + d]) : 0.0f;
    float w = wave_sum(mv);
    if (!(threadIdx.x & 63)) red[threadIdx.x >> 6] = w;
    __syncthreads();
    float cum = red[0] + red[1] + red[2] + red[3];
    int idx = (int)(cum + 0.5f);
    int xv = x[r];
    float acc = emb_b[d];
#pragma unroll
    for (int k = 0; k < 16; k++)
        if ((xv >> k) & 1) acc += emb_W[k * D + d];
    acc *= 16.0f;
    if (use_pos[0]) acc += pos_enc[idx * D + d];
    h[r * D + d] = acc;
}

// ---------- generic row-block GEMM pieces: Br=8, Bc=64, 4-way K-split ----------
// decode packed bf16 pair
#define DECODE(wp, w_lo, w_hi) \
    float w_lo = __uint_as_float((wp) << 16); \
    float w_hi = __uint_as_float((wp) & 0xffff0000u);

// ---------- K2: qkv = h @ wW + wb   (grid (64,4), block 256) ----------
__global__ __launch_bounds__(256) void k_qkv(
    const float* __restrict__ h, const uint32* __restrict__ pw, const float* __restrict__ wb,
    float* __restrict__ qkv)
{
    __shared__ float red[4][8][64];
    int r0 = blockIdx.x * 8, c0 = blockIdx.y * 64;
    int kq = threadIdx.x >> 6, cl = threadIdx.x & 63;
    int c = c0 + cl, k0 = kq * 64;
    float acc[8] = {0.f,0.f,0.f,0.f,0.f,0.f,0.f,0.f};
#pragma unroll 2
    for (int kk = 0; kk < 64; kk += 4) {
        int k = k0 + kk;
        uint32 wpA = pw[(k >> 1) * D + c];
        uint32 wpB = pw[((k >> 1) + 1) * D + c];
        DECODE(wpA, w0, w1); DECODE(wpB, w2v, w3);
#pragma unroll
        for (int r = 0; r < 8; r++) {
            float4 hv = *(const float4*)&h[(r0 + r) * D + k];
            acc[r] = fmaf(hv.x, w0, acc[r]); acc[r] = fmaf(hv.y, w1, acc[r]);
            acc[r] = fmaf(hv.z, w2v, acc[r]); acc[r] = fmaf(hv.w, w3, acc[r]);
        }
    }
#pragma unroll
    for (int r = 0; r < 8; r++) red[kq][r][cl] = acc[r];
    __syncthreads();
    int rg = threadIdx.x >> 6;
#pragma unroll
    for (int p = 0; p < 2; p++) {
        int r = rg + p * 4;
        float s = red[0][r][cl] + red[1][r][cl] + red[2][r][cl] + red[3][r][cl];
        qkv[(r0 + r) * D + c] = s + wb[c];
    }
}

// ---------- K3: qa = qkv@W1a + b1 ; qbT = (qkv@W1b)^T   (grid (64,8), block 256) ----------
__global__ __launch_bounds__(256) void k_qab(
    const float* __restrict__ qkv, const uint32* __restrict__ pw, const float* __restrict__ nnb1,
    float* __restrict__ qa, float* __restrict__ qbT)
{
    __shared__ float red[4][8][64];
    int r0 = blockIdx.x * 8;
    int isB = blockIdx.y >> 2;
    int c0 = (blockIdx.y & 3) * 64;
    const uint32* W = pw + isB * (128 * 256);
    int kq = threadIdx.x >> 6, cl = threadIdx.x & 63;
    int c = c0 + cl, k0 = kq * 64;
    float acc[8] = {0.f,0.f,0.f,0.f,0.f,0.f,0.f,0.f};
#pragma unroll 2
    for (int kk = 0; kk < 64; kk += 4) {
        int k = k0 + kk;
        uint32 wpA = W[(k >> 1) * D + c];
        uint32 wpB = W[((k >> 1) + 1) * D + c];
        DECODE(wpA, w0, w1); DECODE(wpB, w2v, w3);
#pragma unroll
        for (int r = 0; r < 8; r++) {
            float4 hv = *(const float4*)&qkv[(r0 + r) * D + k];
            acc[r] = fmaf(hv.x, w0, acc[r]); acc[r] = fmaf(hv.y, w1, acc[r]);
            acc[r] = fmaf(hv.z, w2v, acc[r]); acc[r] = fmaf(hv.w, w3, acc[r]);
        }
    }
#pragma unroll
    for (int r = 0; r < 8; r++) red[kq][r][cl] = acc[r];
    __syncthreads();
    int rg = threadIdx.x >> 6;
#pragma unroll
    for (int p = 0; p < 2; p++) {
        int r = rg + p * 4;
        float s = red[0][r][cl] + red[1][r][cl] + red[2][r][cl] + red[3][r][cl];
        int row = r0 + r;
        if (!isB) qa[row * D + c] = s + nnb1[c];
        else {
            int b = row >> 8, j = row & 255;
            qbT[b * (S * D) + c * S + j] = s;
        }
    }
}

// ---------- K4: g[b,i,j] = sum_h relu(qa[i,h]+qb[j,h])*w2[h] (grid (64,4), block 256) ----------
__global__ __launch_bounds__(256) void k_g(
    const float* __restrict__ qa, const float* __restrict__ qbT,
    const float* __restrict__ w2, float* __restrict__ g, float* __restrict__ gT)
{
    __shared__ float red[4][8][64];
    int ri0 = blockIdx.x * 8;
    int b = ri0 >> 8;
    int j0 = blockIdx.y * 64;
    int kq = threadIdx.x >> 6, cl = threadIdx.x & 63;
    int k0 = kq * 64;
    const float* qbTb = qbT + b * (S * D);
    float acc[8] = {0.f,0.f,0.f,0.f,0.f,0.f,0.f,0.f};
#pragma unroll 2
    for (int hh = 0; hh < 64; hh += 4) {
        int hgl = k0 + hh;
        float4 wv = *(const float4*)&w2[hgl];
        float b0 = qbTb[(hgl + 0) * S + j0 + cl];
        float b1 = qbTb[(hgl + 1) * S + j0 + cl];
        float b2 = qbTb[(hgl + 2) * S + j0 + cl];
        float b3 = qbTb[(hgl + 3) * S + j0 + cl];
#pragma unroll
        for (int r = 0; r < 8; r++) {
            float4 qv = *(const float4*)&qa[(ri0 + r) * D + hgl];
            acc[r] = fmaf(fmaxf(qv.x + b0, 0.f), wv.x, acc[r]);
            acc[r] = fmaf(fmaxf(qv.y + b1, 0.f), wv.y, acc[r]);
            acc[r] = fmaf(fmaxf(qv.z + b2, 0.f), wv.z, acc[r]);
            acc[r] = fmaf(fmaxf(qv.w + b3, 0.f), wv.w, acc[r]);
        }
    }
#pragma unroll
    for (int r = 0; r < 8; r++) red[kq][r][cl] = acc[r];
    __syncthreads();
    int rg = threadIdx.x >> 6;
#pragma unroll
    for (int p = 0; p < 2; p++) {
        int r = rg + p * 4;
        float s = red[0][r][cl] + red[1][r][cl] + red[2][r][cl] + red[3][r][cl];
        g[(ri0 + r) * S + j0 + cl] = s;
        gT[(b * S + j0 + cl) * S + ((ri0 + r) & 255)] = s;
    }
}

// ---------- K5: softmax row (grid 512, block 256) ----------
__global__ __launch_bounds__(256) void k_soft(
    const float* __restrict__ g, const float* __restrict__ gT,
    const float* __restrict__ mask, const float* __restrict__ b2p,
    float* __restrict__ attn)
{
    __shared__ float redm[4], reds[4];
    int i = blockIdx.x;
    int b = i >> 8;
    int t = threadIdx.x;
    float sv = g[i * S + t] + gT[i * S + t] + 2.0f * b2p[0] + mask[b * S + t] * (-1e9f);
    float wm = wave_max(sv);
    if (!(t & 63)) redm[t >> 6] = wm;
    __syncthreads();
    float m = fmaxf(fmaxf(redm[0], redm[1]), fmaxf(redm[2], redm[3]));
    float e = __expf(sv - m);
    float ws = wave_sum(e);
    if (!(t & 63)) reds[t >> 6] = ws;
    __syncthreads();
    float inv = 1.0f / (reds[0] + reds[1] + reds[2] + reds[3]);
    attn[i * S + t] = e * inv;
}

// ---------- K6: ao = attn @ qkv  (grid (64,4), block 256; f32 V) ----------
__global__ __launch_bounds__(256) void k_av(
    const float* __restrict__ attn, const float* __restrict__ qkv,
    float* __restrict__ ao)
{
    __shared__ float red[4][8][64];
    int r0 = blockIdx.x * 8, c0 = blockIdx.y * 64;
    int b = r0 >> 8;
    const float* W = qkv + b * (S * D);
    int kq = threadIdx.x >> 6, cl = threadIdx.x & 63;
    int c = c0 + cl, k0 = kq * 64;
    float acc[8] = {0.f,0.f,0.f,0.f,0.f,0.f,0.f,0.f};
#pragma unroll 2
    for (int kk = 0; kk < 64; kk += 4) {
        int k = k0 + kk;
        float w0 = W[(k + 0) * D + c], w1 = W[(k + 1) * D + c];
        float w2v = W[(k + 2) * D + c], w3 = W[(k + 3) * D + c];
#pragma unroll
        for (int r = 0; r < 8; r++) {
            float4 av = *(const float4*)&attn[(r0 + r) * S + k];
            acc[r] = fmaf(av.x, w0, acc[r]); acc[r] = fmaf(av.y, w1, acc[r]);
            acc[r] = fmaf(av.z, w2v, acc[r]); acc[r] = fmaf(av.w, w3, acc[r]);
        }
    }
#pragma unroll
    for (int r = 0; r < 8; r++) red[kq][r][cl] = acc[r];
    __syncthreads();
    int rg = threadIdx.x >> 6;
#pragma unroll
    for (int p = 0; p < 2; p++) {
        int r = rg + p * 4;
        float s = red[0][r][cl] + red[1][r][cl] + red[2][r][cl] + red[3][r][cl];
        ao[(r0 + r) * D + c] = s;
    }
}

// ---------- K7: pp = ao @ outW  (grid (64,4), block 256) ----------
__global__ __launch_bounds__(256) void k_proj(
    const float* __restrict__ ao, const uint32* __restrict__ pw, float* __restrict__ pp)
{
    __shared__ float red[4][8][64];
    int r0 = blockIdx.x * 8, c0 = blockIdx.y * 64;
    int kq = threadIdx.x >> 6, cl = threadIdx.x & 63;
    int c = c0 + cl, k0 = kq * 64;
    float acc[8] = {0.f,0.f,0.f,0.f,0.f,0.f,0.f,0.f};
#pragma unroll 2
    for (int kk = 0; kk < 64; kk += 4) {
        int k = k0 + kk;
        uint32 wpA = pw[(k >> 1) * D + c];
        uint32 wpB = pw[((k >> 1) + 1) * D + c];
        DECODE(wpA, w0, w1); DECODE(wpB, w2v, w3);
#pragma unroll
        for (int r = 0; r < 8; r++) {
            float4 hv = *(const float4*)&ao[(r0 + r) * D + k];
            acc[r] = fmaf(hv.x, w0, acc[r]); acc[r] = fmaf(hv.y, w1, acc[r]);
            acc[r] = fmaf(hv.z, w2v, acc[r]); acc[r] = fmaf(hv.w, w3, acc[r]);
        }
    }
#pragma unroll
    for (int r = 0; r < 8; r++) red[kq][r][cl] = acc[r];
    __syncthreads();
    int rg = threadIdx.x >> 6;
#pragma unroll
    for (int p = 0; p < 2; p++) {
        int r = rg + p * 4;
        float s = red[0][r][cl] + red[1][r][cl] + red[2][r][cl] + red[3][r][cl];
        pp[(r0 + r) * D + c] = s;
    }
}

// ---------- K8: o1 = LN1(h + pp + outb)  (grid 512, block 256) ----------
__global__ __launch_bounds__(256) void k_ln1(
    const float* __restrict__ h, const float* __restrict__ pp, const float* __restrict__ outb,
    const float* __restrict__ lng, const float* __restrict__ lnb, float* __restrict__ o1)
{
    __shared__ float red[4];
    int r = blockIdx.x, c = threadIdx.x;
    float v = h[r * D + c] + pp[r * D + c] + outb[c];
    float s1 = wave_sum(v);
    if (!(c & 63)) red[c >> 6] = s1;
    __syncthreads();
    float mu = (red[0] + red[1] + red[2] + red[3]) * (1.0f / 256.0f);
    float dv = v - mu;
    __syncthreads();
    float s2 = wave_sum(dv * dv);
    if (!(c & 63)) red[c >> 6] = s2;
    __syncthreads();
    float var = (red[0] + red[1] + red[2] + red[3]) * (1.0f / 256.0f);
    o1[r * D + c] = dv * rsqrtf(var + 1e-6f) * lng[c] + lnb[c];
}

// ---------- K9: f1 = relu(o1 @ ffnW1 + b1)  (grid (64,16), block 256) ----------
__global__ __launch_bounds__(256) void k_ffn1(
    const float* __restrict__ o1, const uint32* __restrict__ pw, const float* __restrict__ b1,
    float* __restrict__ f1)
{
    __shared__ float red[4][8][64];
    int r0 = blockIdx.x * 8, c0 = blockIdx.y * 64;
    int kq = threadIdx.x >> 6, cl = threadIdx.x & 63;
    int c = c0 + cl, k0 = kq * 64;
    float acc[8] = {0.f,0.f,0.f,0.f,0.f,0.f,0.f,0.f};
#pragma unroll 2
    for (int kk = 0; kk < 64; kk += 4) {
        int k = k0 + kk;
        uint32 wpA = pw[(k >> 1) * DFF + c];
        uint32 wpB = pw[((k >> 1) + 1) * DFF + c];
        DECODE(wpA, w0, w1); DECODE(wpB, w2v, w3);
#pragma unroll
        for (int r = 0; r < 8; r++) {
            float4 hv = *(const float4*)&o1[(r0 + r) * D + k];
            acc[r] = fmaf(hv.x, w0, acc[r]); acc[r] = fmaf(hv.y, w1, acc[r]);
            acc[r] = fmaf(hv.z, w2v, acc[r]); acc[r] = fmaf(hv.w, w3, acc[r]);
        }
    }
#pragma unroll
    for (int r = 0; r < 8; r++) red[kq][r][cl] = acc[r];
    __syncthreads();
    int rg = threadIdx.x >> 6;
#pragma unroll
    for (int p = 0; p < 2; p++) {
        int r = rg + p * 4;
        float s = red[0][r][cl] + red[1][r][cl] + red[2][r][cl] + red[3][r][cl];
        f1[(r0 + r) * DFF + c] = fmaxf(s + b1[c], 0.f);
    }
}

// ---------- K10: f2 = f1 @ ffnW2  (grid (64,4), block 256; K=1024) ----------
__global__ __launch_bounds__(256) void k_ffn2(
    const float* __restrict__ f1, const uint32* __restrict__ pw, float* __restrict__ f2)
{
    __shared__ float red[4][8][64];
    int r0 = blockIdx.x * 8, c0 = blockIdx.y * 64;
    int kq = threadIdx.x >> 6, cl = threadIdx.x & 63;
    int c = c0 + cl, k0 = kq * 256;
    float acc[8] = {0.f,0.f,0.f,0.f,0.f,0.f,0.f,0.f};
#pragma unroll 2
    for (int kk = 0; kk < 256; kk += 4) {
        int k = k0 + kk;
        uint32 wpA = pw[(k >> 1) * D + c];
        uint32 wpB = pw[((k >> 1) + 1) * D + c];
        DECODE(wpA, w0, w1); DECODE(wpB, w2v, w3);
#pragma unroll
        for (int r = 0; r < 8; r++) {
            float4 hv = *(const float4*)&f1[(r0 + r) * DFF + k];
            acc[r] = fmaf(hv.x, w0, acc[r]); acc[r] = fmaf(hv.y, w1, acc[r]);
            acc[r] = fmaf(hv.z, w2v, acc[r]); acc[r] = fmaf(hv.w, w3, acc[r]);
        }
    }
#pragma unroll
    for (int r = 0; r < 8; r++) red[kq][r][cl] = acc[r];
    __syncthreads();
    int rg = threadIdx.x >> 6;
#pragma unroll
    for (int p = 0; p < 2; p++) {
        int r = rg + p * 4;
        float s = red[0][r][cl] + red[1][r][cl] + red[2][r][cl] + red[3][r][cl];
        f2[(r0 + r) * D + c] = s;
    }
}

// ---------- K11: h' = LN2(o1 + f2 + b2)  (grid 512, block 256) ----------
__global__ __launch_bounds__(256) void k_ln2(
    const float* __restrict__ o1, const float* __restrict__ f2, const float* __restrict__ b2,
    const float* __restrict__ lng, const float* __restrict__ lnb, float* __restrict__ hout)
{
    __shared__ float red[4];
    int r = blockIdx.x, c = threadIdx.x;
    float v = o1[r * D + c] + f2[r * D + c] + b2[c];
    float s1 = wave_sum(v);
    if (!(c & 63)) red[c >> 6] = s1;
    __syncthreads();
    float mu = (red[0] + red[1] + red[2] + red[3]) * (1.0f / 256.0f);
    float dv = v - mu;
    __syncthreads();
    float s2 = wave_sum(dv * dv);
    if (!(c & 63)) red[c >> 6] = s2;
    __syncthreads();
    float var = (red[0] + red[1] + red[2] + red[3]) * (1.0f / 256.0f);
    hout[r * D + c] = dv * rsqrtf(var + 1e-6f) * lng[c] + lnb[c];
}

extern "C" void kernel_launch(void* const* d_in, const int* in_sizes, int n_in,
                              void* d_out, int out_size, void* d_ws, size_t ws_size,
                              hipStream_t stream)
{
    const int*   x       = (const int*)d_in[0];
    const float* mask    = (const float*)d_in[1];
    const int*   use_pos = (const int*)d_in[3];
    const float* pos_enc = (const float*)d_in[4];
    const float* emb_W   = (const float*)d_in[5];
    const float* emb_b   = (const float*)d_in[6];
    const float* nn_W1   = (const float*)d_in[7];
    const float* nn_b1   = (const float*)d_in[8];
    const float* nn_W2   = (const float*)d_in[9];
    const float* nn_b2   = (const float*)d_in[10];
    const float* w_W     = (const float*)d_in[11];
    const float* w_b     = (const float*)d_in[12];
    const float* out_W   = (const float*)d_in[13];
    const float* out_b   = (const float*)d_in[14];
    const float* ffn_W1  = (const float*)d_in[15];
    const float* ffn_b1  = (const float*)d_in[16];
    const float* ffn_W2  = (const float*)d_in[17];
    const float* ffn_b2  = (const float*)d_in[18];
    const float* ln1_g   = (const float*)d_in[19];
    const float* ln1_b   = (const float*)d_in[20];
    const float* ln2_g   = (const float*)d_in[21];
    const float* ln2_b   = (const float*)d_in[22];

    float* ws   = (float*)d_ws;
    float* h    = ws;
    float* qkv  = ws + 131072;
    float* qa   = ws + 262144;
    float* qbT  = ws + 393216;
    float* g    = ws + 524288;
    float* gT   = ws + 655360;
    float* attn = ws + 786432;
    float* ao   = ws + 917504;
    float* o1   = ws + 1048576;
    float* f1   = ws + 1179648;      // 524288
    float* pp   = ws + 1703936;      // 131072
    float* f2   = ws + 1835008;      // 131072
    uint32* pwW   = (uint32*)(ws + 1966080);  // 65536
    uint32* pwNN  = (uint32*)(ws + 2031616);  // 65536
    uint32* pwOut = (uint32*)(ws + 2097152);  // 65536
    uint32* pwF1  = (uint32*)(ws + 2162688);  // 262144
    uint32* pwF2  = (uint32*)(ws + 2424832);  // 262144

    k_cvt<<<2816, 256, 0, stream>>>(w_W, nn_W1, out_W, ffn_W1, ffn_W2, pwW);
    k_embed<<<512, 256, 0, stream>>>(x, mask, use_pos, pos_enc, emb_W, emb_b, h);

    for (int l = 0; l < 2; l++) {
        k_qkv<<<dim3(64, 4), 256, 0, stream>>>(h, pwW + l * 32768, w_b + l * D, qkv);
        k_qab<<<dim3(64, 8), 256, 0, stream>>>(qkv, pwNN, nn_b1, qa, qbT);
        k_g<<<dim3(64, 4), 256, 0, stream>>>(qa, qbT, nn_W2, g, gT);
        k_soft<<<512, 256, 0, stream>>>(g, gT, mask, nn_b2, attn);
        k_av<<<dim3(64, 4), 256, 0, stream>>>(attn, qkv, ao);
        k_proj<<<dim3(64, 4), 256, 0, stream>>>(ao, pwOut + l * 32768, pp);
        k_ln1<<<512, 256, 0, stream>>>(h, pp, out_b + l * D, ln1_g + l * D, ln1_b + l * D, o1);
        k_ffn1<<<dim3(64, 16), 256, 0, stream>>>(o1, pwF1 + l * 131072, ffn_b1 + l * DFF, f1);
        k_ffn2<<<dim3(64, 4), 256, 0, stream>>>(f1, pwF2 + l * 131072, f2);
        float* hout = (l == 1) ? (float*)d_out : h;
        k_ln2<<<512, 256, 0, stream>>>(o1, f2, ffn_b2 + l * D, ln2_g + l * D, ln2_b + l * D, hout);
    }
}

// Round 10
// 271.624 us; speedup vs baseline: 1.2240x; 1.2240x over previous
//
#include <hip/hip_runtime.h>

#define S 256
#define D 256
#define DFF 1024

typedef unsigned int uint32;

// ---------------- wave helpers ----------------
__device__ __forceinline__ float wave_sum(float v) {
#pragma unroll
    for (int o = 32; o; o >>= 1) v += __shfl_xor(v, o, 64);
    return v;
}
__device__ __forceinline__ float wave_max(float v) {
#pragma unroll
    for (int o = 32; o; o >>= 1) v = fmaxf(v, __shfl_xor(v, o, 64));
    return v;
}
__device__ __forceinline__ uint32 bf16rne(float f) {
    uint32 u = __float_as_uint(f);
    return (u + 0x7fffu + ((u >> 16) & 1u)) >> 16;
}
#define DECODE(wp, w_lo, w_hi) \
    float w_lo = __uint_as_float((wp) << 16); \
    float w_hi = __uint_as_float((wp) & 0xffff0000u);

// ---------- K0: convert+pack all weights to bf16 row-pairs ----------
__global__ __launch_bounds__(256) void k_cvt(
    const float* __restrict__ wW, const float* __restrict__ nn,
    const float* __restrict__ ow, const float* __restrict__ f1w,
    const float* __restrict__ f2w, uint32* __restrict__ dst)
{
    int i = blockIdx.x * 256 + threadIdx.x;   // 2816*256 = 720896
    const float* src; int local, c;
    if (i < 65536)       { src = wW;  local = i;          c = local & 255; }
    else if (i < 131072) { src = nn;  local = i - 65536;  c = local & 255; }
    else if (i < 196608) { src = ow;  local = i - 131072; c = local & 255; }
    else if (i < 458752) { src = f1w; local = i - 196608; c = local & 1023; }
    else                 { src = f2w; local = i - 458752; c = local & 255; }
    int N = (i >= 196608 && i < 458752) ? 1024 : 256;
    float a0 = src[2 * local - c];
    float a1 = src[2 * local - c + N];
    dst[i] = (bf16rne(a1) << 16) | bf16rne(a0);
}

// ---------- K1: embedding + positional encoding (grid 512, block 256) ----------
__global__ __launch_bounds__(256) void k_embed(
    const int* __restrict__ x, const float* __restrict__ mask,
    const int* __restrict__ use_pos, const float* __restrict__ pos_enc,
    const float* __restrict__ emb_W, const float* __restrict__ emb_b,
    float* __restrict__ h)
{
    __shared__ float red[4];
    int r = blockIdx.x, d = threadIdx.x;
    int b = r >> 8, s = r & 255;
    float mv = (d <= s) ? (1.0f - mask[b * S + d]) : 0.0f;
    float w = wave_sum(mv);
    if (!(threadIdx.x & 63)) red[threadIdx.x >> 6] = w;
    __syncthreads();
    float cum = red[0] + red[1] + red[2] + red[3];
    int idx = (int)(cum + 0.5f);
    int xv = x[r];
    float acc = emb_b[d];
#pragma unroll
    for (int k = 0; k < 16; k++)
        if ((xv >> k) & 1) acc += emb_W[k * D + d];
    acc *= 16.0f;
    if (use_pos[0]) acc += pos_enc[idx * D + d];
    h[r * D + d] = acc;
}

// ================= 1024-thread GEMM blocks: 8 rows x 64 cols, 16-way K-split ==========
// thread (kq = tid>>6 in 0..15, cl = tid&63); LDS combine red[16][8][64] = 32 KB.

// ---------- K2: qkv = h @ wW + wb   (grid (64,4), block 1024, K=256 chunk 16) ----------
__global__ __launch_bounds__(1024) void k_qkv(
    const float* __restrict__ h, const uint32* __restrict__ pw, const float* __restrict__ wb,
    float* __restrict__ qkv)
{
    __shared__ float red[16][8][64];
    int r0 = blockIdx.x * 8, c0 = blockIdx.y * 64;
    int kq = threadIdx.x >> 6, cl = threadIdx.x & 63;
    int c = c0 + cl, k0 = kq * 16;
    float acc[8] = {0.f,0.f,0.f,0.f,0.f,0.f,0.f,0.f};
#pragma unroll
    for (int kk = 0; kk < 16; kk += 4) {
        int k = k0 + kk;
        uint32 wpA = pw[(k >> 1) * D + c];
        uint32 wpB = pw[((k >> 1) + 1) * D + c];
        DECODE(wpA, w0, w1); DECODE(wpB, w2v, w3);
#pragma unroll
        for (int r = 0; r < 8; r++) {
            float4 hv = *(const float4*)&h[(r0 + r) * D + k];
            acc[r] = fmaf(hv.x, w0, acc[r]); acc[r] = fmaf(hv.y, w1, acc[r]);
            acc[r] = fmaf(hv.z, w2v, acc[r]); acc[r] = fmaf(hv.w, w3, acc[r]);
        }
    }
#pragma unroll
    for (int r = 0; r < 8; r++) red[kq][r][cl] = acc[r];
    __syncthreads();
    if (threadIdx.x < 512) {
        int r = threadIdx.x >> 6, cc = threadIdx.x & 63;
        float s = 0.f;
#pragma unroll
        for (int q = 0; q < 16; q++) s += red[q][r][cc];
        qkv[(r0 + r) * D + c0 + cc] = s + wb[c0 + cc];
    }
}

// ---------- K3: qa = qkv@W1a + b1 ; qbT = (qkv@W1b)^T   (grid (64,8), block 1024) ----------
__global__ __launch_bounds__(1024) void k_qab(
    const float* __restrict__ qkv, const uint32* __restrict__ pw, const float* __restrict__ nnb1,
    float* __restrict__ qa, float* __restrict__ qbT)
{
    __shared__ float red[16][8][64];
    int r0 = blockIdx.x * 8;
    int isB = blockIdx.y >> 2;
    int c0 = (blockIdx.y & 3) * 64;
    const uint32* W = pw + isB * (128 * 256);
    int kq = threadIdx.x >> 6, cl = threadIdx.x & 63;
    int c = c0 + cl, k0 = kq * 16;
    float acc[8] = {0.f,0.f,0.f,0.f,0.f,0.f,0.f,0.f};
#pragma unroll
    for (int kk = 0; kk < 16; kk += 4) {
        int k = k0 + kk;
        uint32 wpA = W[(k >> 1) * D + c];
        uint32 wpB = W[((k >> 1) + 1) * D + c];
        DECODE(wpA, w0, w1); DECODE(wpB, w2v, w3);
#pragma unroll
        for (int r = 0; r < 8; r++) {
            float4 hv = *(const float4*)&qkv[(r0 + r) * D + k];
            acc[r] = fmaf(hv.x, w0, acc[r]); acc[r] = fmaf(hv.y, w1, acc[r]);
            acc[r] = fmaf(hv.z, w2v, acc[r]); acc[r] = fmaf(hv.w, w3, acc[r]);
        }
    }
#pragma unroll
    for (int r = 0; r < 8; r++) red[kq][r][cl] = acc[r];
    __syncthreads();
    if (threadIdx.x < 512) {
        int r = threadIdx.x >> 6, cc = threadIdx.x & 63;
        float s = 0.f;
#pragma unroll
        for (int q = 0; q < 16; q++) s += red[q][r][cc];
        int row = r0 + r, col = c0 + cc;
        if (!isB) qa[row * D + col] = s + nnb1[col];
        else {
            int b = row >> 8, j = row & 255;
            qbT[b * (S * D) + col * S + j] = s;
        }
    }
}

// ---------- K4: g[b,i,j] = sum_h relu(qa[i,h]+qb[j,h])*w2[h] (grid (64,4), block 1024) ----------
__global__ __launch_bounds__(1024) void k_g(
    const float* __restrict__ qa, const float* __restrict__ qbT,
    const float* __restrict__ w2, float* __restrict__ g, float* __restrict__ gT)
{
    __shared__ float red[16][8][64];
    int ri0 = blockIdx.x * 8;
    int b = ri0 >> 8;
    int j0 = blockIdx.y * 64;
    int kq = threadIdx.x >> 6, cl = threadIdx.x & 63;
    int k0 = kq * 16;
    const float* qbTb = qbT + b * (S * D);
    float acc[8] = {0.f,0.f,0.f,0.f,0.f,0.f,0.f,0.f};
#pragma unroll
    for (int hh = 0; hh < 16; hh += 4) {
        int hgl = k0 + hh;
        float4 wv = *(const float4*)&w2[hgl];
        float b0 = qbTb[(hgl + 0) * S + j0 + cl];
        float b1 = qbTb[(hgl + 1) * S + j0 + cl];
        float b2 = qbTb[(hgl + 2) * S + j0 + cl];
        float b3 = qbTb[(hgl + 3) * S + j0 + cl];
#pragma unroll
        for (int r = 0; r < 8; r++) {
            float4 qv = *(const float4*)&qa[(ri0 + r) * D + hgl];
            acc[r] = fmaf(fmaxf(qv.x + b0, 0.f), wv.x, acc[r]);
            acc[r] = fmaf(fmaxf(qv.y + b1, 0.f), wv.y, acc[r]);
            acc[r] = fmaf(fmaxf(qv.z + b2, 0.f), wv.z, acc[r]);
            acc[r] = fmaf(fmaxf(qv.w + b3, 0.f), wv.w, acc[r]);
        }
    }
#pragma unroll
    for (int r = 0; r < 8; r++) red[kq][r][cl] = acc[r];
    __syncthreads();
    if (threadIdx.x < 512) {
        int r = threadIdx.x >> 6, cc = threadIdx.x & 63;
        float s = 0.f;
#pragma unroll
        for (int q = 0; q < 16; q++) s += red[q][r][cc];
        g[(ri0 + r) * S + j0 + cc] = s;
        gT[(b * S + j0 + cc) * S + ((ri0 + r) & 255)] = s;
    }
}

// ---------- K5: softmax row (grid 512, block 256) ----------
__global__ __launch_bounds__(256) void k_soft(
    const float* __restrict__ g, const float* __restrict__ gT,
    const float* __restrict__ mask, const float* __restrict__ b2p,
    float* __restrict__ attn)
{
    __shared__ float redm[4], reds[4];
    int i = blockIdx.x;
    int b = i >> 8;
    int t = threadIdx.x;
    float sv = g[i * S + t] + gT[i * S + t] + 2.0f * b2p[0] + mask[b * S + t] * (-1e9f);
    float wm = wave_max(sv);
    if (!(t & 63)) redm[t >> 6] = wm;
    __syncthreads();
    float m = fmaxf(fmaxf(redm[0], redm[1]), fmaxf(redm[2], redm[3]));
    float e = __expf(sv - m);
    float ws = wave_sum(e);
    if (!(t & 63)) reds[t >> 6] = ws;
    __syncthreads();
    float inv = 1.0f / (reds[0] + reds[1] + reds[2] + reds[3]);
    attn[i * S + t] = e * inv;
}

// ---------- K6: ao = attn @ qkv  (grid (64,4), block 1024; f32 V) ----------
__global__ __launch_bounds__(1024) void k_av(
    const float* __restrict__ attn, const float* __restrict__ qkv,
    float* __restrict__ ao)
{
    __shared__ float red[16][8][64];
    int r0 = blockIdx.x * 8, c0 = blockIdx.y * 64;
    int b = r0 >> 8;
    const float* W = qkv + b * (S * D);
    int kq = threadIdx.x >> 6, cl = threadIdx.x & 63;
    int c = c0 + cl, k0 = kq * 16;
    float acc[8] = {0.f,0.f,0.f,0.f,0.f,0.f,0.f,0.f};
#pragma unroll
    for (int kk = 0; kk < 16; kk += 4) {
        int k = k0 + kk;
        float w0 = W[(k + 0) * D + c], w1 = W[(k + 1) * D + c];
        float w2v = W[(k + 2) * D + c], w3 = W[(k + 3) * D + c];
#pragma unroll
        for (int r = 0; r < 8; r++) {
            float4 av = *(const float4*)&attn[(r0 + r) * S + k];
            acc[r] = fmaf(av.x, w0, acc[r]); acc[r] = fmaf(av.y, w1, acc[r]);
            acc[r] = fmaf(av.z, w2v, acc[r]); acc[r] = fmaf(av.w, w3, acc[r]);
        }
    }
#pragma unroll
    for (int r = 0; r < 8; r++) red[kq][r][cl] = acc[r];
    __syncthreads();
    if (threadIdx.x < 512) {
        int r = threadIdx.x >> 6, cc = threadIdx.x & 63;
        float s = 0.f;
#pragma unroll
        for (int q = 0; q < 16; q++) s += red[q][r][cc];
        ao[(r0 + r) * D + c0 + cc] = s;
    }
}

// ---------- K7: pp = ao @ outW  (grid (64,4), block 1024) ----------
__global__ __launch_bounds__(1024) void k_proj(
    const float* __restrict__ ao, const uint32* __restrict__ pw, float* __restrict__ pp)
{
    __shared__ float red[16][8][64];
    int r0 = blockIdx.x * 8, c0 = blockIdx.y * 64;
    int kq = threadIdx.x >> 6, cl = threadIdx.x & 63;
    int c = c0 + cl, k0 = kq * 16;
    float acc[8] = {0.f,0.f,0.f,0.f,0.f,0.f,0.f,0.f};
#pragma unroll
    for (int kk = 0; kk < 16; kk += 4) {
        int k = k0 + kk;
        uint32 wpA = pw[(k >> 1) * D + c];
        uint32 wpB = pw[((k >> 1) + 1) * D + c];
        DECODE(wpA, w0, w1); DECODE(wpB, w2v, w3);
#pragma unroll
        for (int r = 0; r < 8; r++) {
            float4 hv = *(const float4*)&ao[(r0 + r) * D + k];
            acc[r] = fmaf(hv.x, w0, acc[r]); acc[r] = fmaf(hv.y, w1, acc[r]);
            acc[r] = fmaf(hv.z, w2v, acc[r]); acc[r] = fmaf(hv.w, w3, acc[r]);
        }
    }
#pragma unroll
    for (int r = 0; r < 8; r++) red[kq][r][cl] = acc[r];
    __syncthreads();
    if (threadIdx.x < 512) {
        int r = threadIdx.x >> 6, cc = threadIdx.x & 63;
        float s = 0.f;
#pragma unroll
        for (int q = 0; q < 16; q++) s += red[q][r][cc];
        pp[(r0 + r) * D + c0 + cc] = s;
    }
}

// ---------- K8: o1 = LN1(h + pp + outb)  (grid 512, block 256) ----------
__global__ __launch_bounds__(256) void k_ln1(
    const float* __restrict__ h, const float* __restrict__ pp, const float* __restrict__ outb,
    const float* __restrict__ lng, const float* __restrict__ lnb, float* __restrict__ o1)
{
    __shared__ float red[4];
    int r = blockIdx.x, c = threadIdx.x;
    float v = h[r * D + c] + pp[r * D + c] + outb[c];
    float s1 = wave_sum(v);
    if (!(c & 63)) red[c >> 6] = s1;
    __syncthreads();
    float mu = (red[0] + red[1] + red[2] + red[3]) * (1.0f / 256.0f);
    float dv = v - mu;
    __syncthreads();
    float s2 = wave_sum(dv * dv);
    if (!(c & 63)) red[c >> 6] = s2;
    __syncthreads();
    float var = (red[0] + red[1] + red[2] + red[3]) * (1.0f / 256.0f);
    o1[r * D + c] = dv * rsqrtf(var + 1e-6f) * lng[c] + lnb[c];
}

// ---------- K9: f1 = relu(o1 @ ffnW1 + b1)  (grid (64,16), block 1024) ----------
__global__ __launch_bounds__(1024) void k_ffn1(
    const float* __restrict__ o1, const uint32* __restrict__ pw, const float* __restrict__ b1,
    float* __restrict__ f1)
{
    __shared__ float red[16][8][64];
    int r0 = blockIdx.x * 8, c0 = blockIdx.y * 64;
    int kq = threadIdx.x >> 6, cl = threadIdx.x & 63;
    int c = c0 + cl, k0 = kq * 16;
    float acc[8] = {0.f,0.f,0.f,0.f,0.f,0.f,0.f,0.f};
#pragma unroll
    for (int kk = 0; kk < 16; kk += 4) {
        int k = k0 + kk;
        uint32 wpA = pw[(k >> 1) * DFF + c];
        uint32 wpB = pw[((k >> 1) + 1) * DFF + c];
        DECODE(wpA, w0, w1); DECODE(wpB, w2v, w3);
#pragma unroll
        for (int r = 0; r < 8; r++) {
            float4 hv = *(const float4*)&o1[(r0 + r) * D + k];
            acc[r] = fmaf(hv.x, w0, acc[r]); acc[r] = fmaf(hv.y, w1, acc[r]);
            acc[r] = fmaf(hv.z, w2v, acc[r]); acc[r] = fmaf(hv.w, w3, acc[r]);
        }
    }
#pragma unroll
    for (int r = 0; r < 8; r++) red[kq][r][cl] = acc[r];
    __syncthreads();
    if (threadIdx.x < 512) {
        int r = threadIdx.x >> 6, cc = threadIdx.x & 63;
        float s = 0.f;
#pragma unroll
        for (int q = 0; q < 16; q++) s += red[q][r][cc];
        f1[(r0 + r) * DFF + c0 + cc] = fmaxf(s + b1[c0 + cc], 0.f);
    }
}

// ---------- K10: f2 = f1 @ ffnW2  (grid (64,4), block 1024; K=1024 chunk 64) ----------
__global__ __launch_bounds__(1024) void k_ffn2(
    const float* __restrict__ f1, const uint32* __restrict__ pw, float* __restrict__ f2)
{
    __shared__ float red[16][8][64];
    int r0 = blockIdx.x * 8, c0 = blockIdx.y * 64;
    int kq = threadIdx.x >> 6, cl = threadIdx.x & 63;
    int c = c0 + cl, k0 = kq * 64;
    float acc[8] = {0.f,0.f,0.f,0.f,0.f,0.f,0.f,0.f};
#pragma unroll 4
    for (int kk = 0; kk < 64; kk += 4) {
        int k = k0 + kk;
        uint32 wpA = pw[(k >> 1) * D + c];
        uint32 wpB = pw[((k >> 1) + 1) * D + c];
        DECODE(wpA, w0, w1); DECODE(wpB, w2v, w3);
#pragma unroll
        for (int r = 0; r < 8; r++) {
            float4 hv = *(const float4*)&f1[(r0 + r) * DFF + k];
            acc[r] = fmaf(hv.x, w0, acc[r]); acc[r] = fmaf(hv.y, w1, acc[r]);
            acc[r] = fmaf(hv.z, w2v, acc[r]); acc[r] = fmaf(hv.w, w3, acc[r]);
        }
    }
#pragma unroll
    for (int r = 0; r < 8; r++) red[kq][r][cl] = acc[r];
    __syncthreads();
    if (threadIdx.x < 512) {
        int r = threadIdx.x >> 6, cc = threadIdx.x & 63;
        float s = 0.f;
#pragma unroll
        for (int q = 0; q < 16; q++) s += red[q][r][cc];
        f2[(r0 + r) * D + c0 + cc] = s;
    }
}

// ---------- K11: h' = LN2(o1 + f2 + b2)  (grid 512, block 256) ----------
__global__ __launch_bounds__(256) void k_ln2(
    const float* __restrict__ o1, const float* __restrict__ f2, const float* __restrict__ b2,
    const float* __restrict__ lng, const float* __restrict__ lnb, float* __restrict__ hout)
{
    __shared__ float red[4];
    int r = blockIdx.x, c = threadIdx.x;
    float v = o1[r * D + c] + f2[r * D + c] + b2[c];
    float s1 = wave_sum(v);
    if (!(c & 63)) red[c >> 6] = s1;
    __syncthreads();
    float mu = (red[0] + red[1] + red[2] + red[3]) * (1.0f / 256.0f);
    float dv = v - mu;
    __syncthreads();
    float s2 = wave_sum(dv * dv);
    if (!(c & 63)) red[c >> 6] = s2;
    __syncthreads();
    float var = (red[0] + red[1] + red[2] + red[3]) * (1.0f / 256.0f);
    hout[r * D + c] = dv * rsqrtf(var + 1e-6f) * lng[c] + lnb[c];
}

extern "C" void kernel_launch(void* const* d_in, const int* in_sizes, int n_in,
                              void* d_out, int out_size, void* d_ws, size_t ws_size,
                              hipStream_t stream)
{
    const int*   x       = (const int*)d_in[0];
    const float* mask    = (const float*)d_in[1];
    const int*   use_pos = (const int*)d_in[3];
    const float* pos_enc = (const float*)d_in[4];
    const float* emb_W   = (const float*)d_in[5];
    const float* emb_b   = (const float*)d_in[6];
    const float* nn_W1   = (const float*)d_in[7];
    const float* nn_b1   = (const float*)d_in[8];
    const float* nn_W2   = (const float*)d_in[9];
    const float* nn_b2   = (const float*)d_in[10];
    const float* w_W     = (const float*)d_in[11];
    const float* w_b     = (const float*)d_in[12];
    const float* out_W   = (const float*)d_in[13];
    const float* out_b   = (const float*)d_in[14];
    const float* ffn_W1  = (const float*)d_in[15];
    const float* ffn_b1  = (const float*)d_in[16];
    const float* ffn_W2  = (const float*)d_in[17];
    const float* ffn_b2  = (const float*)d_in[18];
    const float* ln1_g   = (const float*)d_in[19];
    const float* ln1_b   = (const float*)d_in[20];
    const float* ln2_g   = (const float*)d_in[21];
    const float* ln2_b   = (const float*)d_in[22];

    float* ws   = (float*)d_ws;
    float* h    = ws;
    float* qkv  = ws + 131072;
    float* qa   = ws + 262144;
    float* qbT  = ws + 393216;
    float* g    = ws + 524288;
    float* gT   = ws + 655360;
    float* attn = ws + 786432;
    float* ao   = ws + 917504;
    float* o1   = ws + 1048576;
    float* f1   = ws + 1179648;      // 524288
    float* pp   = ws + 1703936;      // 131072
    float* f2   = ws + 1835008;      // 131072
    uint32* pwW   = (uint32*)(ws + 1966080);  // 65536
    uint32* pwNN  = (uint32*)(ws + 2031616);  // 65536
    uint32* pwOut = (uint32*)(ws + 2097152);  // 65536
    uint32* pwF1  = (uint32*)(ws + 2162688);  // 262144
    uint32* pwF2  = (uint32*)(ws + 2424832);  // 262144

    k_cvt<<<2816, 256, 0, stream>>>(w_W, nn_W1, out_W, ffn_W1, ffn_W2, pwW);
    k_embed<<<512, 256, 0, stream>>>(x, mask, use_pos, pos_enc, emb_W, emb_b, h);

    for (int l = 0; l < 2; l++) {
        k_qkv<<<dim3(64, 4), 1024, 0, stream>>>(h, pwW + l * 32768, w_b + l * D, qkv);
        k_qab<<<dim3(64, 8), 1024, 0, stream>>>(qkv, pwNN, nn_b1, qa, qbT);
        k_g<<<dim3(64, 4), 1024, 0, stream>>>(qa, qbT, nn_W2, g, gT);
        k_soft<<<512, 256, 0, stream>>>(g, gT, mask, nn_b2, attn);
        k_av<<<dim3(64, 4), 1024, 0, stream>>>(attn, qkv, ao);
        k_proj<<<dim3(64, 4), 1024, 0, stream>>>(ao, pwOut + l * 32768, pp);
        k_ln1<<<512, 256, 0, stream>>>(h, pp, out_b + l * D, ln1_g + l * D, ln1_b + l * D, o1);
        k_ffn1<<<dim3(64, 16), 1024, 0, stream>>>(o1, pwF1 + l * 131072, ffn_b1 + l * DFF, f1);
        k_ffn2<<<dim3(64, 4), 1024, 0, stream>>>(f1, pwF2 + l * 131072, f2);
        float* hout = (l == 1) ? (float*)d_out : h;
        k_ln2<<<512, 256, 0, stream>>>(o1, f2, ffn_b2 + l * D, ln2_g + l * D, ln2_b + l * D, hout);
    }
}